// Round 2
// baseline (24.657 us; speedup 1.0000x reference)
//
#include <hip/hip_runtime.h>

// Exact reference semantics: (sign(t-0.5)+1)*0.5  -> {0, 0.5, 1}
__device__ __forceinline__ float binarize(float t) {
    float d = t - 0.5f;
    float s = (d > 0.0f) ? 1.0f : ((d < 0.0f) ? -1.0f : 0.0f);
    return (s + 1.0f) * 0.5f;
}

// Bank-conflict-free XOR swizzle for float4-indexed LDS.
// Modifies only bits 0-2 -> bijective on any 8-aligned range.
__device__ __forceinline__ int swz(int i) { return i ^ ((i >> 3) & 7); }

__global__ __launch_bounds__(256) void Packetbnn_kernel(
    const float* __restrict__ x,       // [B, 5] flattened
    const float* __restrict__ w_conv,  // [5, 5] flattened
    const float* __restrict__ w_lin,   // [5]
    float* __restrict__ out,           // [B]
    int nquad,                         // number of 4-row quads (B/4)
    int nrows)                         // B
{
    // Block stages 256 quads = 1280 float4s = 20 KB.
    __shared__ float4 lds[1280];

    const int tid = threadIdx.x;
    const long quad0  = (long)blockIdx.x * 256;
    const long base4  = quad0 * 5;            // first float4 index of this block
    const long total4 = (long)nquad * 5;
    const float4* xv = reinterpret_cast<const float4*>(x);

    // Coalesced global loads: lane i reads base + i*16B per instruction.
#pragma unroll
    for (int j = 0; j < 5; ++j) {
        long gi = base4 + j * 256 + tid;
        float4 v = make_float4(0.f, 0.f, 0.f, 0.f);
        if (gi < total4) v = xv[gi];
        int li = j * 256 + tid;
        lds[swz(li)] = v;
    }

    // Binarized weights (uniform addresses, cache-resident) — scheduled
    // alongside the staging loads.
    float wcb[5][5];
#pragma unroll
    for (int o = 0; o < 5; ++o)
#pragma unroll
        for (int k = 0; k < 5; ++k)
            wcb[o][k] = binarize(w_conv[o * 5 + k]);
    float wlb[5];
#pragma unroll
    for (int o = 0; o < 5; ++o) wlb[o] = binarize(w_lin[o]);

    __syncthreads();

    long t = quad0 + tid;
    if (t < nquad) {
        float r[20];
#pragma unroll
        for (int j = 0; j < 5; ++j) {
            float4 v = lds[swz(tid * 5 + j)];
            r[j * 4 + 0] = v.x; r[j * 4 + 1] = v.y;
            r[j * 4 + 2] = v.z; r[j * 4 + 3] = v.w;
        }

        float res[4];
#pragma unroll
        for (int q = 0; q < 4; ++q) {
            float xb[5];
#pragma unroll
            for (int k = 0; k < 5; ++k) xb[k] = binarize(r[q * 5 + k]);
            float acc = 0.0f;
#pragma unroll
            for (int o = 0; o < 5; ++o) {
                float c = 0.0f;
#pragma unroll
                for (int k = 0; k < 5; ++k) c += xb[k] * wcb[o][k];
                acc += binarize(c) * wlb[o];
            }
            res[q] = acc;
        }
        reinterpret_cast<float4*>(out)[t] =
            make_float4(res[0], res[1], res[2], res[3]);
    }

    // Tail rows (nrows % 4 != 0) — normally dead (B = 4194304).
    if (blockIdx.x == 0 && tid == 0) {
        for (int row = nquad * 4; row < nrows; ++row) {
            float xb[5];
            for (int k = 0; k < 5; ++k) xb[k] = binarize(x[(size_t)row * 5 + k]);
            float acc = 0.0f;
            for (int o = 0; o < 5; ++o) {
                float c = 0.0f;
                for (int k = 0; k < 5; ++k) c += xb[k] * wcb[o][k];
                acc += binarize(c) * wlb[o];
            }
            out[row] = acc;
        }
    }
}

extern "C" void kernel_launch(void* const* d_in, const int* in_sizes, int n_in,
                              void* d_out, int out_size, void* d_ws, size_t ws_size,
                              hipStream_t stream) {
    const float* x      = (const float*)d_in[0];  // [B,1,1,5]
    const float* w_conv = (const float*)d_in[1];  // [5,1,1,5]
    const float* w_lin  = (const float*)d_in[2];  // [1,5]
    float* out = (float*)d_out;                   // [B,1]

    int nrows = out_size;          // B
    int nquad = nrows / 4;
    int threads = 256;
    int blocks = (nquad + threads - 1) / threads;
    if (blocks < 1) blocks = 1;

    Packetbnn_kernel<<<blocks, threads, 0, stream>>>(x, w_conv, w_lin, out,
                                                     nquad, nrows);
}

// Round 3
// 21.501 us; speedup vs baseline: 1.1468x; 1.1468x over previous
//
#include <hip/hip_runtime.h>

// Exact reference semantics: (sign(t-0.5)+1)*0.5  -> {0, 0.5, 1}
__device__ __forceinline__ float binarize(float t) {
    float d = t - 0.5f;
    float s = (d > 0.0f) ? 1.0f : ((d < 0.0f) ? -1.0f : 0.0f);
    return (s + 1.0f) * 0.5f;
}

// Involution swizzle on float4 indices: flips low 3 bits by bits 3..5.
// Permutes only within 128B cachelines -> global loads stay line-coalesced;
// makes the stride-5-float4 LDS readback bank-uniform.
__device__ __forceinline__ int swz(int i) { return i ^ ((i >> 3) & 7); }

__global__ __launch_bounds__(256) void Packetbnn_kernel(
    const float* __restrict__ x,       // [B, 5] flattened
    const float* __restrict__ w_conv,  // [5, 5] flattened
    const float* __restrict__ w_lin,   // [5]
    float* __restrict__ out,           // [B]
    int nquad,                         // number of 4-row quads (B/4)
    int nrows)                         // B
{
    // Per-wave slab: 64 quads * 5 float4 = 320 float4 = 5 KB; 4 waves = 20 KB.
    __shared__ float4 lds[1280];

    const int tid  = threadIdx.x;
    const int lane = tid & 63;
    const int wv   = tid >> 6;
    float4* slab = &lds[wv * 320];

    const long quad0  = (long)blockIdx.x * 256;  // block's first quad
    const long wq0    = quad0 + (long)wv * 64;   // wave's first quad
    const long wbase  = wq0 * 5;                 // wave's first float4 index
    const long total4 = (long)nquad * 5;
    const float4* xv = reinterpret_cast<const float4*>(x);

    // Async global->LDS staging, 16B/lane, linear LDS dest (HW requirement),
    // pre-swizzled global source. slab[s] = xv[wbase + swz(s)].
#pragma unroll
    for (int j = 0; j < 5; ++j) {
        int s = j * 64 + lane;
        long gi = wbase + swz(s);
        if (gi < total4) {
            __builtin_amdgcn_global_load_lds(
                (const __attribute__((address_space(1))) void*)(xv + gi),
                (__attribute__((address_space(3))) void*)(slab + j * 64),
                16, 0, 0);
        }
    }

    // Binarized weights (uniform, cache-resident) — overlap with staging.
    float wcb[5][5];
#pragma unroll
    for (int o = 0; o < 5; ++o)
#pragma unroll
        for (int k = 0; k < 5; ++k)
            wcb[o][k] = binarize(w_conv[o * 5 + k]);
    float wlb[5];
#pragma unroll
    for (int o = 0; o < 5; ++o) wlb[o] = binarize(w_lin[o]);

    // Intra-wave visibility: drain the global->LDS queue. No barrier needed.
    asm volatile("s_waitcnt vmcnt(0)" ::: "memory");
    __builtin_amdgcn_sched_barrier(0);

    long t = wq0 + lane;
    if (t < nquad) {
        float r[20];
#pragma unroll
        for (int j = 0; j < 5; ++j) {
            // slab[swz(i)] == xv[wbase + i] (swz is an involution)
            float4 v = slab[swz(5 * lane + j)];
            r[j * 4 + 0] = v.x; r[j * 4 + 1] = v.y;
            r[j * 4 + 2] = v.z; r[j * 4 + 3] = v.w;
        }

        float res[4];
#pragma unroll
        for (int q = 0; q < 4; ++q) {
            float xb[5];
#pragma unroll
            for (int k = 0; k < 5; ++k) xb[k] = binarize(r[q * 5 + k]);
            float acc = 0.0f;
#pragma unroll
            for (int o = 0; o < 5; ++o) {
                float c = 0.0f;
#pragma unroll
                for (int k = 0; k < 5; ++k) c += xb[k] * wcb[o][k];
                acc += binarize(c) * wlb[o];
            }
            res[q] = acc;
        }
        reinterpret_cast<float4*>(out)[t] =
            make_float4(res[0], res[1], res[2], res[3]);
    }

    // Tail rows (nrows % 4 != 0) — normally dead (B = 4194304).
    if (blockIdx.x == 0 && tid == 0) {
        for (int row = nquad * 4; row < nrows; ++row) {
            float xb[5];
            for (int k = 0; k < 5; ++k) xb[k] = binarize(x[(size_t)row * 5 + k]);
            float acc = 0.0f;
            for (int o = 0; o < 5; ++o) {
                float c = 0.0f;
                for (int k = 0; k < 5; ++k) c += xb[k] * wcb[o][k];
                acc += binarize(c) * wlb[o];
            }
            out[row] = acc;
        }
    }
}

extern "C" void kernel_launch(void* const* d_in, const int* in_sizes, int n_in,
                              void* d_out, int out_size, void* d_ws, size_t ws_size,
                              hipStream_t stream) {
    const float* x      = (const float*)d_in[0];  // [B,1,1,5]
    const float* w_conv = (const float*)d_in[1];  // [5,1,1,5]
    const float* w_lin  = (const float*)d_in[2];  // [1,5]
    float* out = (float*)d_out;                   // [B,1]

    int nrows = out_size;          // B
    int nquad = nrows / 4;
    int threads = 256;
    int blocks = (nquad + threads - 1) / threads;
    if (blocks < 1) blocks = 1;

    Packetbnn_kernel<<<blocks, threads, 0, stream>>>(x, w_conv, w_lin, out,
                                                     nquad, nrows);
}